// Round 5
// baseline (135.433 us; speedup 1.0000x reference)
//
#include <hip/hip_runtime.h>
#include <hip/hip_bf16.h>
#include <math.h>

// Problem constants (fixed by setup_inputs)
#define BB 32
#define LL 128
#define DD 300
#define PD 50
#define KW 12          // window K
#define NP 3044        // number of (emo,cau) pairs for L=128, K=12
#define FF 650         // 2*D + pos_dim
#define NR 25          // 2K+1 distinct relative positions
#define KP 320         // K padded for MFMA (10 x 32)
#define NPAD 320       // N padded
#define MM 4096        // B*L
#define LN_EPS 1e-5f

typedef __attribute__((ext_vector_type(8))) short short8;
typedef __attribute__((ext_vector_type(4))) float f32x4;
typedef __attribute__((ext_vector_type(4))) int i32x4;

__device__ __forceinline__ unsigned short f2b(float f) {
    union { float f; unsigned int u; } v; v.f = f;
    unsigned int u = v.u;
    unsigned int r = u + 0x7FFFu + ((u >> 16) & 1u);   // RNE
    return (unsigned short)(r >> 16);
}

__device__ __forceinline__ int row_start(int i) {
    // pairs before emo-row i (L=128, K=12)
    if (i <= 12) return i * 13 + (i * (i - 1)) / 2;
    if (i <= 116) return 222 + 25 * (i - 12);
    int s = i - 116;
    return 2822 + 24 * s - (s * (s - 1)) / 2;
}

// ---------------------------------------------------------------------------
// prep: blocks 0..24      -> P[r][dd] (Gaussian-smoothed pos emb through W3)
//       blocks 25..824    -> Wbf[z][d][k] bf16 ([n][k] layout, zero padded)
// (identical to the round-3 kernel that passed the full harness)
// ---------------------------------------------------------------------------
#define PREP_W_BLOCKS 800    // 2*320*320 / 256

__global__ __launch_bounds__(256) void prep_kernel(
    const float* __restrict__ pos_emb, const float* __restrict__ W_hid,
    const float* __restrict__ b_hid, float* __restrict__ P,
    unsigned short* __restrict__ Wbf)
{
    const int tid = threadIdx.x;
    if (blockIdx.x < NR) {
        __shared__ float sm[PD];
        const int r = blockIdx.x;
        if (tid < PD) {
            float acc = 0.f;
            #pragma unroll
            for (int d = 0; d < NR; d++) {
                int ad = d - KW; if (ad < 0) ad = -ad;
                float cnt = (float)(LL - ad);
                float diff = (float)(r - d);
                acc += cnt * expf(-diff * diff) * pos_emb[d * PD + tid];
            }
            sm[tid] = acc;
        }
        __syncthreads();
        for (int dd = tid; dd < DD; dd += 256) {
            float a = b_hid[dd];
            const float* w = W_hid + dd * FF + 2 * DD;
            #pragma unroll
            for (int k = 0; k < PD; k++) a += sm[k] * w[k];
            P[r * DD + dd] = a;
        }
    } else {
        int idx = (blockIdx.x - NR) * 256 + tid;     // 0 .. 204799
        int z = idx / (NPAD * KP);
        int rem = idx - z * (NPAD * KP);
        int d = rem / KP;
        int k = rem - d * KP;
        unsigned short v = 0;
        if (d < DD && k < DD) v = f2b(W_hid[d * FF + z * DD + k]);
        Wbf[idx] = v;
    }
}

// ---------------------------------------------------------------------------
// MFMA GEMM: O[z][m][d] = sum_k bf16(h_x[m][k]+h_share[m][k]) * Wbf[z][d][k]
// A fragment built in-register from fp32. B tile staged in LDS.
// (identical to the round-3 kernel that passed the full harness)
// ---------------------------------------------------------------------------
__global__ __launch_bounds__(256) void gemm_kernel(
    const float* __restrict__ h_e, const float* __restrict__ h_c,
    const float* __restrict__ h_share, const unsigned short* __restrict__ Wbf,
    float* __restrict__ E, float* __restrict__ Cc)
{
    __shared__ unsigned short Bs[160 * 40];

    const int z = blockIdx.z;
    const int m0 = blockIdx.x * 64;
    const int n0 = blockIdx.y * 160;
    const int tid = threadIdx.x;
    const int wid = tid >> 6;
    const int lane = tid & 63;
    const int nn = lane & 15;          // frag m / n within 16
    const int q  = lane >> 4;          // k-chunk quad

    const int row = m0 + wid * 16 + nn;
    const float* xr = (z ? h_c : h_e) + (size_t)row * DD;
    const float* sr = h_share + (size_t)row * DD;
    const unsigned short* Wbase = Wbf + (size_t)(z * NPAD + n0) * KP;

    f32x4 acc[10];
    #pragma unroll
    for (int f = 0; f < 10; f++) acc[f] = (f32x4){0.f, 0.f, 0.f, 0.f};

    for (int k0 = 0; k0 < KP; k0 += 32) {
        // stage B chunk: 160 rows x 32 k (64B/row) -> LDS, 16B per transfer
        for (int i = tid; i < 640; i += 256) {
            int n = i >> 2;
            int c = i & 3;
            i32x4 v = *(const i32x4*)&Wbase[n * KP + k0 + c * 8];
            *(i32x4*)&Bs[n * 40 + c * 8] = v;
        }
        __syncthreads();

        // build A fragment: 8 k's starting at kb, fp32 add + bf16 round
        const int kb = k0 + q * 8;
        float a8[8];
        if (kb + 7 < DD) {
            float4 x0 = *(const float4*)&xr[kb];
            float4 x1 = *(const float4*)&xr[kb + 4];
            float4 s0 = *(const float4*)&sr[kb];
            float4 s1 = *(const float4*)&sr[kb + 4];
            a8[0] = x0.x + s0.x; a8[1] = x0.y + s0.y;
            a8[2] = x0.z + s0.z; a8[3] = x0.w + s0.w;
            a8[4] = x1.x + s1.x; a8[5] = x1.y + s1.y;
            a8[6] = x1.z + s1.z; a8[7] = x1.w + s1.w;
        } else {
            #pragma unroll
            for (int u = 0; u < 8; u++) {
                int k = kb + u;
                a8[u] = (k < DD) ? (xr[k] + sr[k]) : 0.f;
            }
        }
        short8 a;
        #pragma unroll
        for (int u = 0; u < 8; u++) a[u] = (short)f2b(a8[u]);

        #pragma unroll
        for (int f = 0; f < 10; f++) {
            short8 b = *(const short8*)&Bs[(f * 16 + nn) * 40 + q * 8];
            acc[f] = __builtin_amdgcn_mfma_f32_16x16x32_bf16(a, b, acc[f], 0, 0, 0);
        }
        __syncthreads();
    }

    float* O = z ? Cc : E;
    const int orow = m0 + wid * 16 + q * 4;    // C/D: row = (lane>>4)*4 + reg
    #pragma unroll
    for (int f = 0; f < 10; f++) {
        int col = n0 + f * 16 + nn;            // C/D: col = lane&15
        if (col < DD) {
            #pragma unroll
            for (int r = 0; r < 4; r++)
                O[(size_t)(orow + r) * DD + col] = acc[f][r];
        }
    }
}

// ---------------------------------------------------------------------------
// pair kernel: one 64-thread block per (b, i). 16 lanes per pair: the 4
// quarter-groups process 4 consecutive j's at once (d = (lane&15) + 16t,
// t = 0..18). Butterfly masks <=8 stay inside the 16-lane group, so one
// 4-stage reduction covers 4 pairs. e/ln params register-cached per wave.
// ---------------------------------------------------------------------------
__global__ __launch_bounds__(64) void pair_kernel(
    const float* __restrict__ E, const float* __restrict__ Cc,
    const float* __restrict__ P, const float* __restrict__ ln_g,
    const float* __restrict__ ln_b, const float* __restrict__ W_rel,
    const float* __restrict__ b_rel, float* __restrict__ out)
{
    const int lane = threadIdx.x;          // 0..63
    const int qd = lane >> 4;              // which j within the group of 4
    const int l16 = lane & 15;
    const int slot = blockIdx.x;           // 0 .. 4095
    const int b = slot >> 7;
    const int i = slot & 127;

    const float* e_row = E + (size_t)(b * LL + i) * DD;

    float e[19], g[19], gb[19], wr[19];
    #pragma unroll
    for (int t = 0; t < 19; t++) {
        int d = l16 + 16 * t;
        bool v = d < DD;
        e[t]  = v ? e_row[d] : 0.f;
        g[t]  = v ? ln_g[d]  : 0.f;
        gb[t] = v ? ln_b[d]  : 0.f;
        wr[t] = v ? W_rel[d] : 0.f;
    }
    const float brel = b_rel[0];

    int jlo = i - KW; if (jlo < 0) jlo = 0;
    int jhi = i + KW; if (jhi > LL - 1) jhi = LL - 1;
    const int base = b * NP + row_start(i);

    for (int j0 = jlo; j0 <= jhi; j0 += 4) {
        const int j = j0 + qd;
        const int jc = (j <= jhi) ? j : jhi;           // clamp for safe loads
        const float* c_row = Cc + (size_t)(b * LL + jc) * DD;
        const float* p_row = P + (jc - i + KW) * DD;

        float h[19];
        float s = 0.f, ss = 0.f;
        #pragma unroll
        for (int t = 0; t < 19; t++) {
            int d = l16 + 16 * t;
            float hv = 0.f;
            if (d < DD) {
                hv = e[t] + c_row[d] + p_row[d];
                s += hv;
                ss += hv * hv;
            }
            h[t] = hv;
        }
        #pragma unroll
        for (int m = 1; m < 16; m <<= 1) {
            s  += __shfl_xor(s, m, 64);
            ss += __shfl_xor(ss, m, 64);
        }
        const float mean = s * (1.f / (float)DD);
        float var = ss * (1.f / (float)DD) - mean * mean;
        if (var < 0.f) var = 0.f;
        const float rstd = rsqrtf(var + LN_EPS);

        float acc = 0.f;
        #pragma unroll
        for (int t = 0; t < 19; t++) {
            float A = rstd * g[t];
            float Bc = __builtin_fmaf(-mean, A, gb[t]);
            float y = __builtin_fmaf(h[t], A, Bc);
            float el = y > 0.f ? y : (__expf(y) - 1.f);
            acc = __builtin_fmaf(el, wr[t], acc);
        }
        #pragma unroll
        for (int m = 1; m < 16; m <<= 1) acc += __shfl_xor(acc, m, 64);

        if (l16 == 0 && j <= jhi) out[base + (j - jlo)] = acc + brel;
    }
}

// ---------------------------------------------------------------------------
extern "C" void kernel_launch(void* const* d_in, const int* in_sizes, int n_in,
                              void* d_out, int out_size, void* d_ws, size_t ws_size,
                              hipStream_t stream) {
    const float* h_e     = (const float*)d_in[0];
    const float* h_c     = (const float*)d_in[1];
    const float* h_share = (const float*)d_in[2];
    const float* pos_emb = (const float*)d_in[3];
    const float* W_hid   = (const float*)d_in[4];
    const float* b_hid   = (const float*)d_in[5];
    const float* ln_g    = (const float*)d_in[6];
    const float* ln_b    = (const float*)d_in[7];
    const float* W_rel   = (const float*)d_in[8];
    const float* b_rel   = (const float*)d_in[9];

    float* out = (float*)d_out;

    // workspace layout
    float* ws = (float*)d_ws;
    float* E   = ws;                             // 4096*300 f32
    float* C   = E + (size_t)MM * DD;            // 4096*300 f32
    float* P   = C + (size_t)MM * DD;            // 25*300 f32
    unsigned short* Wbf = (unsigned short*)(P + NR * DD);   // 2*320*320 u16

    // 1) P rows + bf16 weight operand (round-3 proven)
    prep_kernel<<<dim3(NR + PREP_W_BLOCKS), dim3(256), 0, stream>>>(
        pos_emb, W_hid, b_hid, P, Wbf);

    // 2) MFMA GEMMs with in-register A conversion (round-3 proven)
    gemm_kernel<<<dim3(MM / 64, 2, 2), dim3(256), 0, stream>>>(
        h_e, h_c, h_share, Wbf, E, C);

    // 3) per-(b,i) 64-thread block, 4 pairs per 16-lane group: LN + ELU + dot
    pair_kernel<<<dim3(BB * LL), dim3(64), 0, stream>>>(
        E, C, P, ln_g, ln_b, W_rel, b_rel, out);
}

// Round 6
// 134.770 us; speedup vs baseline: 1.0049x; 1.0049x over previous
//
#include <hip/hip_runtime.h>
#include <hip/hip_bf16.h>
#include <math.h>

// Problem constants (fixed by setup_inputs)
#define BB 32
#define LL 128
#define DD 300
#define PD 50
#define KW 12          // window K
#define NP 3044        // number of (emo,cau) pairs for L=128, K=12
#define FF 650         // 2*D + pos_dim
#define NR 25          // 2K+1 distinct relative positions
#define KP 320         // K padded for MFMA (10 x 32)
#define NPAD 320       // N padded
#define MM 4096        // B*L
#define LN_EPS 1e-5f

typedef __attribute__((ext_vector_type(8))) short short8;
typedef __attribute__((ext_vector_type(4))) float f32x4;
typedef __attribute__((ext_vector_type(4))) int i32x4;

__device__ __forceinline__ unsigned short f2b(float f) {
    union { float f; unsigned int u; } v; v.f = f;
    unsigned int u = v.u;
    unsigned int r = u + 0x7FFFu + ((u >> 16) & 1u);   // RNE
    return (unsigned short)(r >> 16);
}

__device__ __forceinline__ int row_start(int i) {
    // pairs before emo-row i (L=128, K=12)
    if (i <= 12) return i * 13 + (i * (i - 1)) / 2;
    if (i <= 116) return 222 + 25 * (i - 12);
    int s = i - 116;
    return 2822 + 24 * s - (s * (s - 1)) / 2;
}

// ---------------------------------------------------------------------------
// prep: blocks 0..24      -> P[r][dd] (Gaussian-smoothed pos emb through W3)
//       blocks 25..824    -> Wbf[z][d][k] bf16 ([n][k] layout, zero padded)
// (byte-identical to the round-3 kernel that passed the full harness twice)
// ---------------------------------------------------------------------------
#define PREP_W_BLOCKS 800    // 2*320*320 / 256

__global__ __launch_bounds__(256) void prep_kernel(
    const float* __restrict__ pos_emb, const float* __restrict__ W_hid,
    const float* __restrict__ b_hid, float* __restrict__ P,
    unsigned short* __restrict__ Wbf)
{
    const int tid = threadIdx.x;
    if (blockIdx.x < NR) {
        __shared__ float sm[PD];
        const int r = blockIdx.x;
        if (tid < PD) {
            float acc = 0.f;
            #pragma unroll
            for (int d = 0; d < NR; d++) {
                int ad = d - KW; if (ad < 0) ad = -ad;
                float cnt = (float)(LL - ad);
                float diff = (float)(r - d);
                acc += cnt * expf(-diff * diff) * pos_emb[d * PD + tid];
            }
            sm[tid] = acc;
        }
        __syncthreads();
        for (int dd = tid; dd < DD; dd += 256) {
            float a = b_hid[dd];
            const float* w = W_hid + dd * FF + 2 * DD;
            #pragma unroll
            for (int k = 0; k < PD; k++) a += sm[k] * w[k];
            P[r * DD + dd] = a;
        }
    } else {
        int idx = (blockIdx.x - NR) * 256 + tid;     // 0 .. 204799
        int z = idx / (NPAD * KP);
        int rem = idx - z * (NPAD * KP);
        int d = rem / KP;
        int k = rem - d * KP;
        unsigned short v = 0;
        if (d < DD && k < DD) v = f2b(W_hid[d * FF + z * DD + k]);
        Wbf[idx] = v;
    }
}

// ---------------------------------------------------------------------------
// MFMA GEMM: O[z][m][d] = sum_k bf16(h_x[m][k]+h_share[m][k]) * Wbf[z][d][k]
// (byte-identical to the round-3 kernel that passed the full harness twice)
// ---------------------------------------------------------------------------
__global__ __launch_bounds__(256) void gemm_kernel(
    const float* __restrict__ h_e, const float* __restrict__ h_c,
    const float* __restrict__ h_share, const unsigned short* __restrict__ Wbf,
    float* __restrict__ E, float* __restrict__ Cc)
{
    __shared__ unsigned short Bs[160 * 40];

    const int z = blockIdx.z;
    const int m0 = blockIdx.x * 64;
    const int n0 = blockIdx.y * 160;
    const int tid = threadIdx.x;
    const int wid = tid >> 6;
    const int lane = tid & 63;
    const int nn = lane & 15;          // frag m / n within 16
    const int q  = lane >> 4;          // k-chunk quad

    const int row = m0 + wid * 16 + nn;
    const float* xr = (z ? h_c : h_e) + (size_t)row * DD;
    const float* sr = h_share + (size_t)row * DD;
    const unsigned short* Wbase = Wbf + (size_t)(z * NPAD + n0) * KP;

    f32x4 acc[10];
    #pragma unroll
    for (int f = 0; f < 10; f++) acc[f] = (f32x4){0.f, 0.f, 0.f, 0.f};

    for (int k0 = 0; k0 < KP; k0 += 32) {
        // stage B chunk: 160 rows x 32 k (64B/row) -> LDS, 16B per transfer
        for (int i = tid; i < 640; i += 256) {
            int n = i >> 2;
            int c = i & 3;
            i32x4 v = *(const i32x4*)&Wbase[n * KP + k0 + c * 8];
            *(i32x4*)&Bs[n * 40 + c * 8] = v;
        }
        __syncthreads();

        // build A fragment: 8 k's starting at kb, fp32 add + bf16 round
        const int kb = k0 + q * 8;
        float a8[8];
        if (kb + 7 < DD) {
            float4 x0 = *(const float4*)&xr[kb];
            float4 x1 = *(const float4*)&xr[kb + 4];
            float4 s0 = *(const float4*)&sr[kb];
            float4 s1 = *(const float4*)&sr[kb + 4];
            a8[0] = x0.x + s0.x; a8[1] = x0.y + s0.y;
            a8[2] = x0.z + s0.z; a8[3] = x0.w + s0.w;
            a8[4] = x1.x + s1.x; a8[5] = x1.y + s1.y;
            a8[6] = x1.z + s1.z; a8[7] = x1.w + s1.w;
        } else {
            #pragma unroll
            for (int u = 0; u < 8; u++) {
                int k = kb + u;
                a8[u] = (k < DD) ? (xr[k] + sr[k]) : 0.f;
            }
        }
        short8 a;
        #pragma unroll
        for (int u = 0; u < 8; u++) a[u] = (short)f2b(a8[u]);

        #pragma unroll
        for (int f = 0; f < 10; f++) {
            short8 b = *(const short8*)&Bs[(f * 16 + nn) * 40 + q * 8];
            acc[f] = __builtin_amdgcn_mfma_f32_16x16x32_bf16(a, b, acc[f], 0, 0, 0);
        }
        __syncthreads();
    }

    float* O = z ? Cc : E;
    const int orow = m0 + wid * 16 + q * 4;    // C/D: row = (lane>>4)*4 + reg
    #pragma unroll
    for (int f = 0; f < 10; f++) {
        int col = n0 + f * 16 + nn;            // C/D: col = lane&15
        if (col < DD) {
            #pragma unroll
            for (int r = 0; r < 4; r++)
                O[(size_t)(orow + r) * DD + col] = acc[f][r];
        }
    }
}

// ---------------------------------------------------------------------------
// pair kernel: 256-thread block = 4 waves, each wave owns one (b,i) slot.
// Within a wave, the 4 16-lane groups process 4 consecutive j's at once.
// Lane l16 covers d = 4*l16 + 64*t (float4, t=0..4). Exact boundary:
// at t=4, the float4 is fully valid iff l16 < 11 (lanes 0..10 cover
// d=256..299 exactly) — no OOB loads, no per-component masks.
// Butterfly masks <=8 stay inside the 16-lane group.
// ---------------------------------------------------------------------------
__global__ __launch_bounds__(256) void pair_kernel(
    const float* __restrict__ E, const float* __restrict__ Cc,
    const float* __restrict__ P, const float* __restrict__ ln_g,
    const float* __restrict__ ln_b, const float* __restrict__ W_rel,
    const float* __restrict__ b_rel, float* __restrict__ out)
{
    const int tid = threadIdx.x;
    const int wid = tid >> 6;
    const int lane = tid & 63;
    const int qd = lane >> 4;              // which j within the group of 4
    const int l16 = lane & 15;
    const int slot = blockIdx.x * 4 + wid; // 0 .. 4095
    const int b = slot >> 7;
    const int i = slot & 127;

    const bool t4v = (l16 < 11);           // t=4 float4 fully valid
    const float* e_row = E + (size_t)(b * LL + i) * DD;
    const float4 z4 = make_float4(0.f, 0.f, 0.f, 0.f);

    float4 e4[5], g4[5], gb4[5], wr4[5];
    #pragma unroll
    for (int t = 0; t < 5; t++) {
        int d = 4 * l16 + 64 * t;
        bool v = (t < 4) | t4v;
        e4[t]  = v ? *(const float4*)&e_row[d] : z4;
        g4[t]  = v ? *(const float4*)&ln_g[d]  : z4;
        gb4[t] = v ? *(const float4*)&ln_b[d]  : z4;
        wr4[t] = v ? *(const float4*)&W_rel[d] : z4;
    }
    const float brel = b_rel[0];

    int jlo = i - KW; if (jlo < 0) jlo = 0;
    int jhi = i + KW; if (jhi > LL - 1) jhi = LL - 1;
    const int base = b * NP + row_start(i);

    for (int j0 = jlo; j0 <= jhi; j0 += 4) {
        const int j = j0 + qd;
        const int jc = (j <= jhi) ? j : jhi;           // clamp for safe loads
        const float* c_row = Cc + (size_t)(b * LL + jc) * DD;
        const float* p_row = P + (jc - i + KW) * DD;

        float4 h4[5];
        float s = 0.f, ss = 0.f;
        #pragma unroll
        for (int t = 0; t < 5; t++) {
            int d = 4 * l16 + 64 * t;
            bool v = (t < 4) | t4v;
            float4 c4 = v ? *(const float4*)&c_row[d] : z4;
            float4 p4 = v ? *(const float4*)&p_row[d] : z4;
            float4 hv;
            hv.x = e4[t].x + c4.x + p4.x;
            hv.y = e4[t].y + c4.y + p4.y;
            hv.z = e4[t].z + c4.z + p4.z;
            hv.w = e4[t].w + c4.w + p4.w;
            h4[t] = hv;
            s  += hv.x + hv.y + hv.z + hv.w;
            ss += hv.x * hv.x + hv.y * hv.y + hv.z * hv.z + hv.w * hv.w;
        }
        #pragma unroll
        for (int m = 1; m < 16; m <<= 1) {
            s  += __shfl_xor(s, m, 64);
            ss += __shfl_xor(ss, m, 64);
        }
        const float mean = s * (1.f / (float)DD);
        float var = ss * (1.f / (float)DD) - mean * mean;
        if (var < 0.f) var = 0.f;
        const float rstd = rsqrtf(var + LN_EPS);

        float acc = 0.f;
        #pragma unroll
        for (int t = 0; t < 5; t++) {
            #pragma unroll
            for (int c = 0; c < 4; c++) {
                float hc = (c == 0) ? h4[t].x : (c == 1) ? h4[t].y
                         : (c == 2) ? h4[t].z : h4[t].w;
                float gc = (c == 0) ? g4[t].x : (c == 1) ? g4[t].y
                         : (c == 2) ? g4[t].z : g4[t].w;
                float gbc = (c == 0) ? gb4[t].x : (c == 1) ? gb4[t].y
                          : (c == 2) ? gb4[t].z : gb4[t].w;
                float wrc = (c == 0) ? wr4[t].x : (c == 1) ? wr4[t].y
                          : (c == 2) ? wr4[t].z : wr4[t].w;
                float A = rstd * gc;
                float Bc = __builtin_fmaf(-mean, A, gbc);
                float y = __builtin_fmaf(hc, A, Bc);
                float el = y > 0.f ? y : (__expf(y) - 1.f);
                acc = __builtin_fmaf(el, wrc, acc);
            }
        }
        #pragma unroll
        for (int m = 1; m < 16; m <<= 1) acc += __shfl_xor(acc, m, 64);

        if (l16 == 0 && j <= jhi) out[base + (j - jlo)] = acc + brel;
    }
}

// ---------------------------------------------------------------------------
extern "C" void kernel_launch(void* const* d_in, const int* in_sizes, int n_in,
                              void* d_out, int out_size, void* d_ws, size_t ws_size,
                              hipStream_t stream) {
    const float* h_e     = (const float*)d_in[0];
    const float* h_c     = (const float*)d_in[1];
    const float* h_share = (const float*)d_in[2];
    const float* pos_emb = (const float*)d_in[3];
    const float* W_hid   = (const float*)d_in[4];
    const float* b_hid   = (const float*)d_in[5];
    const float* ln_g    = (const float*)d_in[6];
    const float* ln_b    = (const float*)d_in[7];
    const float* W_rel   = (const float*)d_in[8];
    const float* b_rel   = (const float*)d_in[9];

    float* out = (float*)d_out;

    // workspace layout
    float* ws = (float*)d_ws;
    float* E   = ws;                             // 4096*300 f32
    float* C   = E + (size_t)MM * DD;            // 4096*300 f32
    float* P   = C + (size_t)MM * DD;            // 25*300 f32
    unsigned short* Wbf = (unsigned short*)(P + NR * DD);   // 2*320*320 u16

    // 1) P rows + bf16 weight operand (round-3 proven)
    prep_kernel<<<dim3(NR + PREP_W_BLOCKS), dim3(256), 0, stream>>>(
        pos_emb, W_hid, b_hid, P, Wbf);

    // 2) MFMA GEMMs with in-register A conversion (round-3 proven)
    gemm_kernel<<<dim3(MM / 64, 2, 2), dim3(256), 0, stream>>>(
        h_e, h_c, h_share, Wbf, E, C);

    // 3) per-(b,i) wave (4 per block), float4 loads, 4 pairs per 16-lane group
    pair_kernel<<<dim3(BB * LL / 4), dim3(256), 0, stream>>>(
        E, C, P, ln_g, ln_b, W_rel, b_rel, out);
}